// Round 6
// baseline (398.102 us; speedup 1.0000x reference)
//
#include <hip/hip_runtime.h>
#include <stdint.h>

// Problem dims (fixed by the reference): B=2048, T=512, F=64, H=16, 4H=64.
#define Bdim 2048
#define Tdim 512
#define NTILE 32                 // 32 tiles of 16 timesteps
#define ROWS 4                   // batch rows per wave (= DPP 16-lane rows)

typedef __attribute__((ext_vector_type(8))) short bf16x8;   // 8 bf16, 4 VGPRs
typedef __attribute__((ext_vector_type(4))) float f32x4;

union U32x4 { uint32_t u[4]; bf16x8 v; };

__device__ __forceinline__ uint16_t f2bf(float f) {
    union { float f; uint32_t u; } v; v.f = f;
    uint32_t r = v.u + 0x7fffu + ((v.u >> 16) & 1u);
    return (uint16_t)(r >> 16);
}
__device__ __forceinline__ float sigmoidf(float z) {
    return __builtin_amdgcn_rcpf(1.0f + __expf(-z));
}
__device__ __forceinline__ float fast_exp2(float x) {
#if __has_builtin(__builtin_amdgcn_exp2f)
    return __builtin_amdgcn_exp2f(x);
#else
    return exp2f(x);
#endif
}

// Init-time probe: which source index does row_ror:M deliver to this lane?
// (same DPP control 0x120|M as the asm fmac below -> direction-proof)
#define RORI(M, dst, src)                                                     \
    dst = __builtin_amdgcn_update_dpp((src), (src), 0x120 | (M), 0xF, 0xF, 0)

// Rotate-fused FMA: ACC += row_ror:M(H) * W  -- ONE VALU instruction.
#define FMAC_ROR(M, ACC, H, W)                                                \
    asm("v_fmac_f32 %0, %1, %2 row_ror:" #M " row_mask:0xf bank_mask:0xf"     \
        : "+v"(ACC) : "v"(H), "v"(W))

// 512 single-wave blocks, FOUR batch rows per wave (lane = rs*16 + u).
// Each lane owns hidden unit u of row rs and computes ALL FOUR gates
// in-lane -> the entire recurrence (dot, activation, c/h update) has ZERO
// cross-lane operations; h re-enters the next step's dot via DPP row_ror,
// which rotates within 16-lane rows = within one batch row.
// Per step: 64 rotate-fused v_fmac_f32_dpp (4 gates x 16 k, serving 4 rows
// per instruction) + 3 sigmoids (pre-scaled by -log2e) + relu + c/h update
// + 1 prefetched ds_read_b128 of z. No DS latency in the serial chain.
// xz = x@Wx + b via per-row MFMA into zbuf[t][rs][u][gate] (double-buffered);
// scan read = contiguous 1KB per wave -> conflict-free.
__global__ __launch_bounds__(64, 1) void lstm_fused(
    const float* __restrict__ x, const float* __restrict__ Wx,
    const float* __restrict__ bias, const float* __restrict__ Wh,
    const float* __restrict__ W2, const float* __restrict__ b2,
    const float* __restrict__ W3, const float* __restrict__ b3,
    const float* __restrict__ Wo, const float* __restrict__ bo,
    float* __restrict__ out)
{
    __shared__ __align__(16) float zbuf[8192];   // [2 buf][t 16][rs 4][u 16][g 4]
    __shared__ float hb[64];

    const int lane = threadIdx.x;
    const int u    = lane & 15;      // hidden unit (within 16-lane DPP row)
    const int quad = lane >> 4;      // scan: batch row rs; proj: MFMA q
    const int b0   = blockIdx.x * ROWS;
    const float NL2E = -1.4426950408889634f;     // -log2(e)

    // ---- per-gate Wh columns, rows permuted to match row_ror:m ----
    // w[g][k] = Wh[idx(k)][g*16+u] * s(g), s = -log2e for sigmoid gates.
    int idx[16];
    idx[0] = u;
#define PR(M) RORI(M, idx[M], u);
    PR(1)  PR(2)  PR(3)  PR(4)  PR(5)  PR(6)  PR(7)
    PR(8)  PR(9)  PR(10) PR(11) PR(12) PR(13) PR(14) PR(15)
#undef PR
    float w[4][16];
    #pragma unroll
    for (int g = 0; g < 4; ++g) {
        const float s = (g == 2) ? 1.0f : NL2E;
        #pragma unroll
        for (int k = 0; k < 16; ++k)
            w[g][k] = Wh[(size_t)idx[k] * 64 + g * 16 + u] * s;
    }

    // ---- Wx as MFMA B-frags (gate-scaled), bias (shared by all rows) ----
    // B[k = kc*32 + quad*8 + e][n = u] = Wx[f][nt*16+u] * s(nt)
    bf16x8 wxf[4][2];
    float bv[4];
    #pragma unroll
    for (int nt = 0; nt < 4; ++nt) {
        const float s = (nt == 2) ? 1.0f : NL2E;
        #pragma unroll
        for (int kc = 0; kc < 2; ++kc)
            #pragma unroll
            for (int e = 0; e < 8; ++e)
                wxf[nt][kc][e] = (short)f2bf(
                    Wx[(size_t)(kc * 32 + quad * 8 + e) * 64 + nt * 16 + u] * s);
        bv[nt] = bias[nt * 16 + u] * s;
    }

    // ---- x tile registers: one 16-step tile for all 4 rows (single buffer;
    // proj consumes before xload overwrites -> WAR order; reload latency is
    // hidden under the following 16-step scan) ----
    f32x4 xa[ROWS][4];
    auto xload = [&](int tile) {
        #pragma unroll
        for (int rs = 0; rs < ROWS; ++rs) {
            const float* p = x + ((size_t)(b0 + rs) * Tdim + tile * 16 + u) * 64
                               + quad * 8;
            xa[rs][0] = *(const f32x4*)(p);
            xa[rs][1] = *(const f32x4*)(p + 4);
            xa[rs][2] = *(const f32x4*)(p + 32);
            xa[rs][3] = *(const f32x4*)(p + 36);
        }
    };

    // Per row rs: A[m = t16][k] = x tile, D[m=t][n=u] with t = quad*4+r.
    // w4 = {acc_nt[r]}_{nt=0..3} = (i,f,g,o) of (t, unit u, row rs) -> one
    // b128 write at zbuf[buf][t][rs][u][0..3].
    auto proj = [&](int buf) {
        #pragma unroll
        for (int rs = 0; rs < ROWS; ++rs) {
            U32x4 af0, af1;
            asm("v_cvt_pk_bf16_f32 %0, %1, %2" : "=v"(af0.u[0]) : "v"(xa[rs][0][0]), "v"(xa[rs][0][1]));
            asm("v_cvt_pk_bf16_f32 %0, %1, %2" : "=v"(af0.u[1]) : "v"(xa[rs][0][2]), "v"(xa[rs][0][3]));
            asm("v_cvt_pk_bf16_f32 %0, %1, %2" : "=v"(af0.u[2]) : "v"(xa[rs][1][0]), "v"(xa[rs][1][1]));
            asm("v_cvt_pk_bf16_f32 %0, %1, %2" : "=v"(af0.u[3]) : "v"(xa[rs][1][2]), "v"(xa[rs][1][3]));
            asm("v_cvt_pk_bf16_f32 %0, %1, %2" : "=v"(af1.u[0]) : "v"(xa[rs][2][0]), "v"(xa[rs][2][1]));
            asm("v_cvt_pk_bf16_f32 %0, %1, %2" : "=v"(af1.u[1]) : "v"(xa[rs][2][2]), "v"(xa[rs][2][3]));
            asm("v_cvt_pk_bf16_f32 %0, %1, %2" : "=v"(af1.u[2]) : "v"(xa[rs][3][0]), "v"(xa[rs][3][1]));
            asm("v_cvt_pk_bf16_f32 %0, %1, %2" : "=v"(af1.u[3]) : "v"(xa[rs][3][2]), "v"(xa[rs][3][3]));
            f32x4 a0 = {bv[0], bv[0], bv[0], bv[0]};
            f32x4 a1 = {bv[1], bv[1], bv[1], bv[1]};
            f32x4 a2 = {bv[2], bv[2], bv[2], bv[2]};
            f32x4 a3 = {bv[3], bv[3], bv[3], bv[3]};
            a0 = __builtin_amdgcn_mfma_f32_16x16x32_bf16(af0.v, wxf[0][0], a0, 0, 0, 0);
            a0 = __builtin_amdgcn_mfma_f32_16x16x32_bf16(af1.v, wxf[0][1], a0, 0, 0, 0);
            a1 = __builtin_amdgcn_mfma_f32_16x16x32_bf16(af0.v, wxf[1][0], a1, 0, 0, 0);
            a1 = __builtin_amdgcn_mfma_f32_16x16x32_bf16(af1.v, wxf[1][1], a1, 0, 0, 0);
            a2 = __builtin_amdgcn_mfma_f32_16x16x32_bf16(af0.v, wxf[2][0], a2, 0, 0, 0);
            a2 = __builtin_amdgcn_mfma_f32_16x16x32_bf16(af1.v, wxf[2][1], a2, 0, 0, 0);
            a3 = __builtin_amdgcn_mfma_f32_16x16x32_bf16(af0.v, wxf[3][0], a3, 0, 0, 0);
            a3 = __builtin_amdgcn_mfma_f32_16x16x32_bf16(af1.v, wxf[3][1], a3, 0, 0, 0);
            float* zb = zbuf + buf * 4096 + quad * 1024 + rs * 64 + u * 4;
            #pragma unroll
            for (int r = 0; r < 4; ++r) {
                float4 w4;
                w4.x = a0[r]; w4.y = a1[r]; w4.z = a2[r]; w4.w = a3[r];
                *(float4*)(zb + r * 256) = w4;
            }
        }
    };

    // ---- prologue ----
    xload(0);
    proj(0);
    xload(1);

    float c = 0.f, h = 0.f;
    // scan-side z pointers: lane (rs=quad, u) reads zbuf[buf][t][quad][u][0..3]
    f32x4 zc = *(const f32x4*)(zbuf + quad * 64 + u * 4);   // buf0, t=0

    auto scan_tile = [&](int n) {
        const float* zp = zbuf + (n & 1) * 4096 + quad * 64 + u * 4;
        const float* zo = zbuf + ((n & 1) ^ 1) * 4096 + quad * 64 + u * 4;
        #pragma unroll
        for (int t = 0; t < 16; ++t) {
            // prefetch next step's z (t=15: next tile's t=0 in other buffer;
            // at the very last tile this reads in-bounds stale data, unused)
            const float* zq = (t < 15) ? (zp + (t + 1) * 256) : zo;
            f32x4 zn = *(const f32x4*)zq;

            // DPP hazard fence: >=2 cycles between h's producer and the
            // rotate-fused fmacs (data-dep pins placement).
            asm volatile("s_nop 1" : "+v"(h));

            // 4 gate pre-activations, all in-lane; k=0 term plain FMA
            float ai = fmaf(h, w[0][0], zc[0]);
            float afv = fmaf(h, w[1][0], zc[1]);
            float ag = fmaf(h, w[2][0], zc[2]);
            float ao = fmaf(h, w[3][0], zc[3]);
#define DOT4(M) FMAC_ROR(M, ai, h, w[0][M]); FMAC_ROR(M, afv, h, w[1][M]);    \
                FMAC_ROR(M, ag, h, w[2][M]); FMAC_ROR(M, ao, h, w[3][M]);
            DOT4(1)  DOT4(2)  DOT4(3)  DOT4(4)  DOT4(5)  DOT4(6)  DOT4(7)
            DOT4(8)  DOT4(9)  DOT4(10) DOT4(11) DOT4(12) DOT4(13) DOT4(14)
            DOT4(15)
#undef DOT4

            // sigmoid lanes hold -z*log2e: sig = rcp(1+2^w); g is relu
            const float si = __builtin_amdgcn_rcpf(1.0f + fast_exp2(ai));
            const float sf = __builtin_amdgcn_rcpf(1.0f + fast_exp2(afv));
            const float so = __builtin_amdgcn_rcpf(1.0f + fast_exp2(ao));
            const float gg = fmaxf(ag, 0.0f);

            c = fmaf(sf, c, si * gg);
            h = so * fmaxf(c, 0.0f);            // h = o * relu(c_new)
            zc = zn;
        }
    };

    // ---- main loop ----
    #pragma unroll 1
    for (int n = 0; n < NTILE; ++n) {
        if (n + 1 < NTILE) proj((n + 1) & 1);   // consumes xa (tile n+1)
        if (n + 2 < NTILE) xload(n + 2);        // WAR after proj; hidden by scan
        scan_tile(n);
    }

    // ---- MLP head: h lives in lane (rs, u); 4 lanes finish 4 rows ----
    hb[quad * 16 + u] = h;                      // single wave: DS in-order
    if (lane < ROWS) {
        const float* hp = &hb[lane * 16];
        float x2[8];
        #pragma unroll
        for (int k = 0; k < 8; ++k) {
            float s = b2[k];
            #pragma unroll
            for (int q = 0; q < 16; ++q) s = fmaf(hp[q], W2[(size_t)q * 8 + k], s);
            x2[k] = fmaxf(s, 0.f);
        }
        float x3[4];
        #pragma unroll
        for (int m = 0; m < 4; ++m) {
            float s = b3[m];
            #pragma unroll
            for (int k = 0; k < 8; ++k) s = fmaf(x2[k], W3[(size_t)k * 4 + m], s);
            x3[m] = fmaxf(s, 0.f);
        }
        float s = bo[0];
        #pragma unroll
        for (int m = 0; m < 4; ++m) s = fmaf(x3[m], Wo[m], s);
        out[b0 + lane] = sigmoidf(s);
    }
}

extern "C" void kernel_launch(void* const* d_in, const int* in_sizes, int n_in,
                              void* d_out, int out_size, void* d_ws, size_t ws_size,
                              hipStream_t stream) {
    const float* x  = (const float*)d_in[0];
    const float* Wx = (const float*)d_in[1];
    const float* Wh = (const float*)d_in[2];
    const float* bb = (const float*)d_in[3];
    const float* W2 = (const float*)d_in[4];
    const float* b2 = (const float*)d_in[5];
    const float* W3 = (const float*)d_in[6];
    const float* b3 = (const float*)d_in[7];
    const float* Wo = (const float*)d_in[8];
    const float* bo = (const float*)d_in[9];

    // 4 batch rows per single-wave block: 512 blocks -> 2 waves/CU.
    lstm_fused<<<Bdim / ROWS, 64, 0, stream>>>(x, Wx, bb, Wh, W2, b2, W3, b3,
                                               Wo, bo, (float*)d_out);
}